// Round 4
// baseline (675.838 us; speedup 1.0000x reference)
//
#include <hip/hip_runtime.h>

#define N_NODES 50000
#define N_EDGES 800000
#define D_FEAT 32
#define NUM_GRAPHS 64
#define FEATS 320
#define NB ((N_NODES + 127) / 128)   // 391 dst-buckets of 128 nodes

// bf16 helpers (RNE pack, shift unpack) — values finite, no NaN path needed
__device__ __forceinline__ unsigned short f2bf(float f) {
    unsigned int u = __float_as_uint(f);
    u = (u + 0x7fffu + ((u >> 16) & 1u)) >> 16;
    return (unsigned short)u;
}
__device__ __forceinline__ float bf2f(unsigned short h) {
    return __uint_as_float((unsigned int)h << 16);
}

// ---------------- CSR construction ----------------

__global__ void hist_kernel(const int* __restrict__ dst, int* __restrict__ deg, int n) {
    int e = blockIdx.x * blockDim.x + threadIdx.x;
    if (e < n) atomicAdd(&deg[dst[e]], 1);
}

__global__ void scan1_kernel(const int* __restrict__ deg, int* __restrict__ inc,
                             int* __restrict__ blksum, int n) {
    __shared__ int s[1024];
    int t = threadIdx.x;
    int i = blockIdx.x * 1024 + t;
    int v = (i < n) ? deg[i] : 0;
    s[t] = v;
    __syncthreads();
    for (int off = 1; off < 1024; off <<= 1) {
        int u = (t >= off) ? s[t - off] : 0;
        __syncthreads();
        s[t] += u;
        __syncthreads();
    }
    if (i < n) inc[i] = s[t];
    if (t == 1023) blksum[blockIdx.x] = s[1023];
}

__global__ void scan2_kernel(const int* __restrict__ blksum, int* __restrict__ blkoff, int nblk) {
    __shared__ int s[64];
    int t = threadIdx.x;
    int v = (t < nblk) ? blksum[t] : 0;
    s[t] = v;
    __syncthreads();
    for (int off = 1; off < 64; off <<= 1) {
        int u = (t >= off) ? s[t - off] : 0;
        __syncthreads();
        s[t] += u;
        __syncthreads();
    }
    if (t < nblk) blkoff[t] = s[t] - v;   // exclusive
}

__global__ void scan3_kernel(const int* __restrict__ deg, const int* __restrict__ inc,
                             const int* __restrict__ blkoff, int* __restrict__ rowptr,
                             int* __restrict__ bktcur, int n, int nedges) {
    int i = blockIdx.x * blockDim.x + threadIdx.x;
    if (i < n) {
        int ex = inc[i] - deg[i] + blkoff[i >> 10];
        rowptr[i] = ex;
        if ((i & 127) == 0) bktcur[i >> 7] = ex;   // bucket region start
    }
    if (i == 0) rowptr[n] = nedges;
}

// phase 1: bucket-grouped scatter. Writes random only within ~16KB bucket regions
// -> full-line write combining in L2. Pack src(16b)|dstLocal(7b)<<16 + w.
__global__ void scatter1_kernel(const int* __restrict__ src, const int* __restrict__ dst,
                                const float* __restrict__ w, int* __restrict__ bktcur,
                                int2* __restrict__ tmp, int n) {
    int e = blockIdx.x * blockDim.x + threadIdx.x;
    if (e < n) {
        int d = dst[e];
        int pos = atomicAdd(&bktcur[d >> 7], 1);
        tmp[pos] = make_int2(src[e] | ((d & 127) << 16), __float_as_int(w[e]));
    }
}

// phase 2: one block per bucket; LDS cursors place edges at exact CSR offsets.
__global__ void scatter2_kernel(const int* __restrict__ rowptr, const int2* __restrict__ tmp,
                                int2* __restrict__ edges, int n) {
    __shared__ int rp[129];
    __shared__ int cur[128];
    int b = blockIdx.x;
    int node0 = b << 7;
    int nloc = min(128, n - node0);
    int t = threadIdx.x;
    if (t <= 128) rp[t] = rowptr[min(node0 + t, n)];
    if (t < 128) cur[t] = 0;
    __syncthreads();
    int e0 = rp[0], e1 = rp[nloc];
    for (int e = e0 + t; e < e1; e += blockDim.x) {
        int2 p = tmp[e];
        int dl = (p.x >> 16) & 127;
        int pos = rp[dl] + atomicAdd(&cur[dl], 1);
        edges[pos] = make_int2(p.x & 0xffff, p.y);
    }
}

// ---------------- X -> bf16 conversion ----------------

__global__ void cvt_kernel(const float4* __restrict__ xin, ushort4* __restrict__ xout, int n4) {
    int i = blockIdx.x * blockDim.x + threadIdx.x;
    if (i < n4) {
        float4 v = xin[i];
        ushort4 o;
        o.x = f2bf(v.x); o.y = f2bf(v.y); o.z = f2bf(v.z); o.w = f2bf(v.w);
        xout[i] = o;
    }
}

// ---------------- graph boundaries (batch is sorted) ----------------

__global__ void gbound_kernel(const int* __restrict__ batch, int* __restrict__ gstart, int n) {
    int i = blockIdx.x * blockDim.x + threadIdx.x;
    if (i >= n) return;
    int g = batch[i];
    int gp = (i == 0) ? -1 : batch[i - 1];
    for (int gg = gp + 1; gg <= g; ++gg) gstart[gg] = i;
    if (i == n - 1)
        for (int gg = g + 1; gg <= NUM_GRAPHS; ++gg) gstart[gg] = n;
}

// ---------------- SpMM (pull, no atomics), D=32 bf16 ----------------
// 16 lanes/node; lane owns cols 2l,2l+1 (ushort2). fp32 accumulate, bf16 store.
// Edge records loaded non-temporally (streamed; keep x resident in per-XCD L2).

__global__ void spmm_kernel(const ushort2* __restrict__ xin,
                            ushort2* __restrict__ yout,
                            const int* __restrict__ rowptr,
                            const long long* __restrict__ edges, int n) {
    int lane = threadIdx.x & 15;
    int node = (blockIdx.x * blockDim.x + threadIdx.x) >> 4;
    if (node >= n) return;
    int e0 = rowptr[node], e1 = rowptr[node + 1];
    float ax = 0.f, ay = 0.f;
    int e = e0;
    int e8 = e0 + ((e1 - e0) & ~7);
    for (; e < e8; e += 8) {
        long long q[8];
        #pragma unroll
        for (int u = 0; u < 8; ++u)
            q[u] = __builtin_nontemporal_load(&edges[e + u]);
        ushort2 v[8];
        #pragma unroll
        for (int u = 0; u < 8; ++u)
            v[u] = xin[(size_t)(unsigned int)(q[u] & 0xffff) * 16 + lane];
        #pragma unroll
        for (int u = 0; u < 8; ++u) {
            float w = __int_as_float((int)(q[u] >> 32));
            ax += bf2f(v[u].x) * w;
            ay += bf2f(v[u].y) * w;
        }
    }
    for (; e < e1; ++e) {
        long long q = __builtin_nontemporal_load(&edges[e]);
        ushort2 v = xin[(size_t)(unsigned int)(q & 0xffff) * 16 + lane];
        float w = __int_as_float((int)(q >> 32));
        ax += bf2f(v.x) * w;
        ay += bf2f(v.y) * w;
    }
    yout[(size_t)node * 16 + lane] = make_ushort2(f2bf(ax), f2bf(ay));
}

// ---------------- fused pooling: 10 terms, 64 graphs x 16 slices ----------------
// term k covers out cols [32k, 32k+32); Q==nullptr -> raw P, else |P - Q|
// branch-free inner loop (no graph-boundary checks), one atomic per col per block

struct PoolArgs10 {
    const unsigned short* P[10];
    const unsigned short* Q[10];
};

__global__ __launch_bounds__(320) void pool_kernel(PoolArgs10 a, const int* __restrict__ gstart,
                                                   float* __restrict__ out) {
    int k = threadIdx.x >> 5;
    int f = threadIdx.x & 31;
    int g = blockIdx.x >> 4;
    int s = blockIdx.x & 15;
    int gs = gstart[g], ge = gstart[g + 1];
    int len = ge - gs;
    int i0 = gs + ((len * s) >> 4);
    int i1 = gs + ((len * (s + 1)) >> 4);
    const unsigned short* __restrict__ P = a.P[k];
    const unsigned short* __restrict__ Q = a.Q[k];
    float acc = 0.f;
    if (Q) {
        for (int i = i0; i < i1; ++i)
            acc += fabsf(bf2f(P[(size_t)i * 32 + f]) - bf2f(Q[(size_t)i * 32 + f]));
    } else {
        for (int i = i0; i < i1; ++i)
            acc += bf2f(P[(size_t)i * 32 + f]);
    }
    if (i1 > i0) atomicAdd(&out[g * FEATS + k * 32 + f], acc);
}

__global__ void divide_kernel(float* __restrict__ out, const int* __restrict__ gstart, int total) {
    int i = blockIdx.x * blockDim.x + threadIdx.x;
    if (i < total) {
        int g = i / FEATS;
        float c = (float)(gstart[g + 1] - gstart[g]);
        out[i] /= fmaxf(c, 1.0f);
    }
}

// ---------------- host launch ----------------

extern "C" void kernel_launch(void* const* d_in, const int* in_sizes, int n_in,
                              void* d_out, int out_size, void* d_ws, size_t ws_size,
                              hipStream_t stream) {
    const float* X     = (const float*)d_in[0];
    const int*   ei    = (const int*)d_in[1];
    const float* ew    = (const float*)d_in[2];
    const int*   batch = (const int*)d_in[3];
    float* out = (float*)d_out;

    const int N = N_NODES, E = N_EDGES;
    const int* src = ei;
    const int* dst = ei + E;

    char* base = (char*)d_ws;
    size_t off = 0;
    auto alloc = [&](size_t bytes) -> void* {
        void* p = base + off;
        off += (bytes + 255) & ~(size_t)255;
        return p;
    };
    // bf16 diffusion chain buffers y[k] = P^k X, k=0..12 (y[0] = bf16(X))
    unsigned short* y[13];
    for (int k = 0; k <= 12; ++k) y[k] = (unsigned short*)alloc((size_t)N * 32 * 2);

    int*  deg    = (int*)alloc((size_t)N * 4);
    int*  inc    = (int*)alloc((size_t)N * 4);
    int*  rowptr = (int*)alloc((size_t)(N + 4) * 4);
    int*  bktcur = (int*)alloc((size_t)(NB + 4) * 4);
    int*  blksum = (int*)alloc(64 * 4);
    int*  blkoff = (int*)alloc(64 * 4);
    int*  gstart = (int*)alloc((NUM_GRAPHS + 1) * 4);
    int2* tmp    = (int2*)alloc((size_t)E * 8);
    int2* edges  = (int2*)alloc((size_t)E * 8);

    hipMemsetAsync(deg, 0, (size_t)N * 4, stream);
    hipMemsetAsync(out, 0, (size_t)out_size * 4, stream);

    // CSR by dst (two-phase bucketed scatter)
    hist_kernel<<<(E + 255) / 256, 256, 0, stream>>>(dst, deg, E);
    const int NBLK = (N + 1023) / 1024; // 49
    scan1_kernel<<<NBLK, 1024, 0, stream>>>(deg, inc, blksum, N);
    scan2_kernel<<<1, 64, 0, stream>>>(blksum, blkoff, NBLK);
    scan3_kernel<<<(N + 255) / 256, 256, 0, stream>>>(deg, inc, blkoff, rowptr, bktcur, N, E);
    scatter1_kernel<<<(E + 255) / 256, 256, 0, stream>>>(src, dst, ew, bktcur, tmp, E);
    scatter2_kernel<<<NB, 256, 0, stream>>>(rowptr, tmp, edges, N);

    // X -> bf16; graph boundaries
    cvt_kernel<<<(N * 32 / 4 + 255) / 256, 256, 0, stream>>>((const float4*)X, (ushort4*)y[0],
                                                             N * 32 / 4);
    gbound_kernel<<<(N + 255) / 256, 256, 0, stream>>>(batch, gstart, N);

    // ---- single D=32 bf16 diffusion chain: y[k] = P y[k-1], k = 1..12
    const int SPMM_GRID = (N * 16) / 256;  // 3125 blocks, 16 nodes/block
    for (int k = 1; k <= 12; ++k) {
        spmm_kernel<<<SPMM_GRID, 256, 0, stream>>>((const ushort2*)y[k - 1], (ushort2*)y[k],
                                                   rowptr, (const long long*)edges, N);
    }

    // ---- fused pooling of all 10 feature column-blocks
    // F0 = y8 | F1: |y1-y2|, |y2-y4|, |y4-y8|
    // F2 (ref order): |y3-y2|, |y5-y3|, |y9-y5|, |y6-y4|, |y10-y6|, |y12-y8|
    {
        PoolArgs10 p{};
        const unsigned short* Ps[10] = {y[8], y[1], y[2], y[4], y[3], y[5], y[9], y[6], y[10], y[12]};
        const unsigned short* Qs[10] = {nullptr, y[2], y[4], y[8], y[2], y[3], y[5], y[4], y[6], y[8]};
        for (int k = 0; k < 10; ++k) { p.P[k] = Ps[k]; p.Q[k] = Qs[k]; }
        pool_kernel<<<NUM_GRAPHS * 16, 320, 0, stream>>>(p, gstart, out);
    }

    divide_kernel<<<(out_size + 255) / 256, 256, 0, stream>>>(out, gstart, out_size);
}

// Round 5
// 345.505 us; speedup vs baseline: 1.9561x; 1.9561x over previous
//
#include <hip/hip_runtime.h>

#define N_NODES 50000
#define N_EDGES 800000
#define D_FEAT 32
#define NUM_GRAPHS 64
#define FEATS 320
#define NBKT (N_NODES / 4)              // 12500 dst-buckets of 4 nodes (low atomic contention)
#define NB2 ((N_NODES + 127) / 128)     // 391 phase-2 blocks of 128 nodes

// bf16 helpers (RNE pack, shift unpack) — values finite, no NaN path needed
__device__ __forceinline__ unsigned short f2bf(float f) {
    unsigned int u = __float_as_uint(f);
    u = (u + 0x7fffu + ((u >> 16) & 1u)) >> 16;
    return (unsigned short)u;
}
__device__ __forceinline__ float bf2f(unsigned short h) {
    return __uint_as_float((unsigned int)h << 16);
}

// ---------------- CSR construction ----------------

__global__ void hist_kernel(const int* __restrict__ dst, int* __restrict__ deg, int n) {
    int e = blockIdx.x * blockDim.x + threadIdx.x;
    if (e < n) atomicAdd(&deg[dst[e]], 1);
}

__global__ void scan1_kernel(const int* __restrict__ deg, int* __restrict__ inc,
                             int* __restrict__ blksum, int n) {
    __shared__ int s[1024];
    int t = threadIdx.x;
    int i = blockIdx.x * 1024 + t;
    int v = (i < n) ? deg[i] : 0;
    s[t] = v;
    __syncthreads();
    for (int off = 1; off < 1024; off <<= 1) {
        int u = (t >= off) ? s[t - off] : 0;
        __syncthreads();
        s[t] += u;
        __syncthreads();
    }
    if (i < n) inc[i] = s[t];
    if (t == 1023) blksum[blockIdx.x] = s[1023];
}

__global__ void scan2_kernel(const int* __restrict__ blksum, int* __restrict__ blkoff, int nblk) {
    __shared__ int s[64];
    int t = threadIdx.x;
    int v = (t < nblk) ? blksum[t] : 0;
    s[t] = v;
    __syncthreads();
    for (int off = 1; off < 64; off <<= 1) {
        int u = (t >= off) ? s[t - off] : 0;
        __syncthreads();
        s[t] += u;
        __syncthreads();
    }
    if (t < nblk) blkoff[t] = s[t] - v;   // exclusive
}

__global__ void scan3_kernel(const int* __restrict__ deg, const int* __restrict__ inc,
                             const int* __restrict__ blkoff, int* __restrict__ rowptr,
                             int* __restrict__ bktcur, int n, int nedges) {
    int i = blockIdx.x * blockDim.x + threadIdx.x;
    if (i < n) {
        int ex = inc[i] - deg[i] + blkoff[i >> 10];
        rowptr[i] = ex;
        if ((i & 3) == 0) bktcur[i >> 2] = ex;   // bucket region start (4 nodes/bucket)
    }
    if (i == 0) rowptr[n] = nedges;
}

// phase 1: bucket-grouped scatter. 12500 counters -> ~64 collisions/counter
// (calibrated: ~330 cyc per same-address atomic -> ~9 us). Writes confined to
// ~512B bucket regions -> L2 line packing. Pack src(16b) | dstLocal128(7b)<<16.
__global__ void scatter1_kernel(const int* __restrict__ src, const int* __restrict__ dst,
                                const float* __restrict__ w, int* __restrict__ bktcur,
                                int2* __restrict__ tmp, int n) {
    int e = blockIdx.x * blockDim.x + threadIdx.x;
    if (e < n) {
        int d = dst[e];
        int pos = atomicAdd(&bktcur[d >> 2], 1);
        tmp[pos] = make_int2(src[e] | ((d & 127) << 16), __float_as_int(w[e]));
    }
}

// phase 2: one block per 128 nodes (32 buckets); LDS cursors place edges at
// exact CSR offsets. Reads contiguous, writes confined to block's CSR range.
__global__ void scatter2_kernel(const int* __restrict__ rowptr, const int2* __restrict__ tmp,
                                int2* __restrict__ edges, int n) {
    __shared__ int rp[129];
    __shared__ int cur[128];
    int b = blockIdx.x;
    int node0 = b << 7;
    int nloc = min(128, n - node0);
    int t = threadIdx.x;
    if (t <= 128) rp[t] = rowptr[min(node0 + t, n)];
    if (t < 128) cur[t] = 0;
    __syncthreads();
    int e0 = rp[0], e1 = rp[nloc];
    for (int e = e0 + t; e < e1; e += blockDim.x) {
        int2 p = tmp[e];
        int dl = (p.x >> 16) & 127;
        int pos = rp[dl] + atomicAdd(&cur[dl], 1);
        edges[pos] = make_int2(p.x & 0xffff, p.y);
    }
}

// ---------------- X -> bf16 conversion ----------------

__global__ void cvt_kernel(const float4* __restrict__ xin, ushort4* __restrict__ xout, int n4) {
    int i = blockIdx.x * blockDim.x + threadIdx.x;
    if (i < n4) {
        float4 v = xin[i];
        ushort4 o;
        o.x = f2bf(v.x); o.y = f2bf(v.y); o.z = f2bf(v.z); o.w = f2bf(v.w);
        xout[i] = o;
    }
}

// ---------------- graph boundaries (batch is sorted) ----------------

__global__ void gbound_kernel(const int* __restrict__ batch, int* __restrict__ gstart, int n) {
    int i = blockIdx.x * blockDim.x + threadIdx.x;
    if (i >= n) return;
    int g = batch[i];
    int gp = (i == 0) ? -1 : batch[i - 1];
    for (int gg = gp + 1; gg <= g; ++gg) gstart[gg] = i;
    if (i == n - 1)
        for (int gg = g + 1; gg <= NUM_GRAPHS; ++gg) gstart[gg] = n;
}

// ---------------- SpMM (pull, no atomics), D=32 bf16 ----------------
// 8 lanes/node; lane owns cols 4l..4l+3 (ushort4, 8B). Wave covers 8 nodes:
// gather instr touches 8 x 64B rows -> half the VMEM instr count of 16-lane
// layout, 8 independent per-node streams per wave. fp32 accum, bf16 store.

__global__ void spmm_kernel(const ushort4* __restrict__ xin,
                            ushort4* __restrict__ yout,
                            const int* __restrict__ rowptr,
                            const int2* __restrict__ edges, int n) {
    int lane = threadIdx.x & 7;
    int node = (blockIdx.x * blockDim.x + threadIdx.x) >> 3;
    if (node >= n) return;
    int e0 = rowptr[node], e1 = rowptr[node + 1];
    float a0 = 0.f, a1 = 0.f, a2 = 0.f, a3 = 0.f;
    int e = e0;
    int e4 = e0 + ((e1 - e0) & ~3);
    for (; e < e4; e += 4) {
        int2 p0 = edges[e + 0];
        int2 p1 = edges[e + 1];
        int2 p2 = edges[e + 2];
        int2 p3 = edges[e + 3];
        ushort4 v0 = xin[(size_t)p0.x * 8 + lane];
        ushort4 v1 = xin[(size_t)p1.x * 8 + lane];
        ushort4 v2 = xin[(size_t)p2.x * 8 + lane];
        ushort4 v3 = xin[(size_t)p3.x * 8 + lane];
        float w0 = __int_as_float(p0.y), w1 = __int_as_float(p1.y);
        float w2 = __int_as_float(p2.y), w3 = __int_as_float(p3.y);
        a0 += bf2f(v0.x) * w0; a1 += bf2f(v0.y) * w0; a2 += bf2f(v0.z) * w0; a3 += bf2f(v0.w) * w0;
        a0 += bf2f(v1.x) * w1; a1 += bf2f(v1.y) * w1; a2 += bf2f(v1.z) * w1; a3 += bf2f(v1.w) * w1;
        a0 += bf2f(v2.x) * w2; a1 += bf2f(v2.y) * w2; a2 += bf2f(v2.z) * w2; a3 += bf2f(v2.w) * w2;
        a0 += bf2f(v3.x) * w3; a1 += bf2f(v3.y) * w3; a2 += bf2f(v3.z) * w3; a3 += bf2f(v3.w) * w3;
    }
    for (; e < e1; ++e) {
        int2 p = edges[e];
        ushort4 v = xin[(size_t)p.x * 8 + lane];
        float w = __int_as_float(p.y);
        a0 += bf2f(v.x) * w; a1 += bf2f(v.y) * w; a2 += bf2f(v.z) * w; a3 += bf2f(v.w) * w;
    }
    yout[(size_t)node * 8 + lane] = make_ushort4(f2bf(a0), f2bf(a1), f2bf(a2), f2bf(a3));
}

// ---------------- fused pooling: 10 terms, 64 graphs x 16 slices ----------------

struct PoolArgs10 {
    const unsigned short* P[10];
    const unsigned short* Q[10];
};

__global__ __launch_bounds__(320) void pool_kernel(PoolArgs10 a, const int* __restrict__ gstart,
                                                   float* __restrict__ out) {
    int k = threadIdx.x >> 5;
    int f = threadIdx.x & 31;
    int g = blockIdx.x >> 4;
    int s = blockIdx.x & 15;
    int gs = gstart[g], ge = gstart[g + 1];
    int len = ge - gs;
    int i0 = gs + ((len * s) >> 4);
    int i1 = gs + ((len * (s + 1)) >> 4);
    const unsigned short* __restrict__ P = a.P[k];
    const unsigned short* __restrict__ Q = a.Q[k];
    float acc = 0.f;
    if (Q) {
        for (int i = i0; i < i1; ++i)
            acc += fabsf(bf2f(P[(size_t)i * 32 + f]) - bf2f(Q[(size_t)i * 32 + f]));
    } else {
        for (int i = i0; i < i1; ++i)
            acc += bf2f(P[(size_t)i * 32 + f]);
    }
    if (i1 > i0) atomicAdd(&out[g * FEATS + k * 32 + f], acc);
}

__global__ void divide_kernel(float* __restrict__ out, const int* __restrict__ gstart, int total) {
    int i = blockIdx.x * blockDim.x + threadIdx.x;
    if (i < total) {
        int g = i / FEATS;
        float c = (float)(gstart[g + 1] - gstart[g]);
        out[i] /= fmaxf(c, 1.0f);
    }
}

// ---------------- host launch ----------------

extern "C" void kernel_launch(void* const* d_in, const int* in_sizes, int n_in,
                              void* d_out, int out_size, void* d_ws, size_t ws_size,
                              hipStream_t stream) {
    const float* X     = (const float*)d_in[0];
    const int*   ei    = (const int*)d_in[1];
    const float* ew    = (const float*)d_in[2];
    const int*   batch = (const int*)d_in[3];
    float* out = (float*)d_out;

    const int N = N_NODES, E = N_EDGES;
    const int* src = ei;
    const int* dst = ei + E;

    char* base = (char*)d_ws;
    size_t off = 0;
    auto alloc = [&](size_t bytes) -> void* {
        void* p = base + off;
        off += (bytes + 255) & ~(size_t)255;
        return p;
    };
    // bf16 diffusion chain buffers y[k] = P^k X, k=0..12 (y[0] = bf16(X))
    unsigned short* y[13];
    for (int k = 0; k <= 12; ++k) y[k] = (unsigned short*)alloc((size_t)N * 32 * 2);

    int*  deg    = (int*)alloc((size_t)N * 4);
    int*  inc    = (int*)alloc((size_t)N * 4);
    int*  rowptr = (int*)alloc((size_t)(N + 4) * 4);
    int*  bktcur = (int*)alloc((size_t)(NBKT + 4) * 4);
    int*  blksum = (int*)alloc(64 * 4);
    int*  blkoff = (int*)alloc(64 * 4);
    int*  gstart = (int*)alloc((NUM_GRAPHS + 1) * 4);
    int2* tmp    = (int2*)alloc((size_t)E * 8);
    int2* edges  = (int2*)alloc((size_t)E * 8);

    hipMemsetAsync(deg, 0, (size_t)N * 4, stream);
    hipMemsetAsync(out, 0, (size_t)out_size * 4, stream);

    // CSR by dst (two-phase bucketed scatter, fine buckets)
    hist_kernel<<<(E + 255) / 256, 256, 0, stream>>>(dst, deg, E);
    const int NBLK = (N + 1023) / 1024; // 49
    scan1_kernel<<<NBLK, 1024, 0, stream>>>(deg, inc, blksum, N);
    scan2_kernel<<<1, 64, 0, stream>>>(blksum, blkoff, NBLK);
    scan3_kernel<<<(N + 255) / 256, 256, 0, stream>>>(deg, inc, blkoff, rowptr, bktcur, N, E);
    scatter1_kernel<<<(E + 255) / 256, 256, 0, stream>>>(src, dst, ew, bktcur, tmp, E);
    scatter2_kernel<<<NB2, 256, 0, stream>>>(rowptr, tmp, edges, N);

    // X -> bf16; graph boundaries
    cvt_kernel<<<(N * 32 / 4 + 255) / 256, 256, 0, stream>>>((const float4*)X, (ushort4*)y[0],
                                                             N * 32 / 4);
    gbound_kernel<<<(N + 255) / 256, 256, 0, stream>>>(batch, gstart, N);

    // ---- single D=32 bf16 diffusion chain: y[k] = P y[k-1], k = 1..12
    const int SPMM_GRID = (N * 8 + 255) / 256;  // 1563 blocks, 32 nodes/block
    for (int k = 1; k <= 12; ++k) {
        spmm_kernel<<<SPMM_GRID, 256, 0, stream>>>((const ushort4*)y[k - 1], (ushort4*)y[k],
                                                   rowptr, (const int2*)edges, N);
    }

    // ---- fused pooling of all 10 feature column-blocks
    // F0 = y8 | F1: |y1-y2|, |y2-y4|, |y4-y8|
    // F2 (ref order): |y3-y2|, |y5-y3|, |y9-y5|, |y6-y4|, |y10-y6|, |y12-y8|
    {
        PoolArgs10 p{};
        const unsigned short* Ps[10] = {y[8], y[1], y[2], y[4], y[3], y[5], y[9], y[6], y[10], y[12]};
        const unsigned short* Qs[10] = {nullptr, y[2], y[4], y[8], y[2], y[3], y[5], y[4], y[6], y[8]};
        for (int k = 0; k < 10; ++k) { p.P[k] = Ps[k]; p.Q[k] = Qs[k]; }
        pool_kernel<<<NUM_GRAPHS * 16, 320, 0, stream>>>(p, gstart, out);
    }

    divide_kernel<<<(out_size + 255) / 256, 256, 0, stream>>>(out, gstart, out_size);
}